// Round 16
// baseline (1462.919 us; speedup 1.0000x reference)
//
#include <hip/hip_runtime.h>
#include <math.h>

#define D 64
#define BR 128          // rows per block
#define NCHUNK 8        // column chunks per op — unit granularity (1024 cols, 8 sub-tiles)
#define YLD 72          // y-tile row stride in bf16 (64 + 8 pad -> 2-way banks only)
#define NPERS 768       // persistent blocks = 256 CUs x 3 blocks/CU
#define LOG2E 1.4426950408889634f
#define LN2   0.6931471805599453f

typedef __attribute__((ext_vector_type(8))) __bf16 bf16x8;
typedef __attribute__((ext_vector_type(4))) float  floatx4;
typedef __attribute__((ext_vector_type(2))) float  floatx2;

static __device__ __forceinline__ float exp2fast(float x) {
#if __has_builtin(__builtin_amdgcn_exp2f)
    return __builtin_amdgcn_exp2f(x);
#else
    return exp2f(x);
#endif
}
static __device__ __forceinline__ float log2fast(float x) {
#if __has_builtin(__builtin_amdgcn_logf)
    return __builtin_amdgcn_logf(x);
#else
    return log2f(x);
#endif
}
static __device__ __forceinline__ float max3f(float a, float b, float c) {
    return fmaxf(fmaxf(a, b), c);   // folds to v_max3_f32
}

static __device__ __forceinline__ unsigned short f2bf_rne(float f) {
    unsigned u = __float_as_uint(f);
    return (unsigned short)((u + 0x7fffu + ((u >> 16) & 1u)) >> 16);
}

// ---------- op descriptors ----------
struct OpDesc {
    const unsigned short* xh;   // [n_rows][64] bf16 row points
    const unsigned short* yh;   // [n_cols][64] bf16 col points
    const float* cc;            // [n_cols] log2-domain col constants
    const float* sqn_col;       // [n_cols]
    float* pm; float* ps;       // [NCHUNK][n_rows]
    int n_rows, n_cols, symmetric, pad;
};
struct P4 { OpDesc op[4]; };

struct MDesc {
    const float* pm; const float* ps;
    const float* sqn_row;
    const float* oldpot;
    float* newpot;
    float* ccout;               // next phase's col constants (crosswired) or null
    float wlog_c;
    int n_rows, mix, pad;
};
struct M4 { MDesc op[4]; };

// ---------- prep kernels ----------
__global__ void cvt_kernel(const float* __restrict__ x,
                           unsigned short* __restrict__ xh, int n_elem8)
{
    int i = blockIdx.x * blockDim.x + threadIdx.x;
    if (i >= n_elem8) return;
    const float4* xp = (const float4*)x;
    float4 v0 = xp[i * 2], v1 = xp[i * 2 + 1];
    float v[8] = {v0.x, v0.y, v0.z, v0.w, v1.x, v1.y, v1.z, v1.w};
    unsigned h[8];
#pragma unroll
    for (int k = 0; k < 8; ++k) h[k] = f2bf_rne(v[k]);
    uint4 ph;
    ph.x = h[0] | (h[1] << 16); ph.y = h[2] | (h[3] << 16);
    ph.z = h[4] | (h[5] << 16); ph.w = h[6] | (h[7] << 16);
    ((uint4*)xh)[i] = ph;
}

__global__ void sqnorm_kernel(const float* __restrict__ x, float* __restrict__ sqn, int n)
{
    int i = blockIdx.x * blockDim.x + threadIdx.x;
    if (i >= n) return;
    const float4* xp = (const float4*)(x + (size_t)i * D);
    float sum = 0.0f;
#pragma unroll
    for (int k = 0; k < D / 4; ++k) {
        float4 v = xp[k];
        sum += v.x * v.x + v.y * v.y + v.z * v.z + v.w * v.w;
    }
    sqn[i] = 0.5f * sum;
}

__global__ void init_cc_kernel(const float* __restrict__ sqn_x, const float* __restrict__ sqn_y,
                               float* cc0, float* cc1, float* cc2, float* cc3,
                               const float* __restrict__ eps_list,
                               float a_log, float b_log, int N, int M,
                               int* __restrict__ counter)
{
    int i = blockIdx.x * blockDim.x + threadIdx.x;
    if (i == 0) counter[0] = 0;    // work-stealing counter init (ws is poisoned pre-call)
    float inv_e0 = 1.0f / eps_list[0];
    if (i < M) { float v = (b_log - sqn_y[i] * inv_e0) * LOG2E; cc0[i] = v; cc3[i] = v; }
    if (i < N) { float v = (a_log - sqn_x[i] * inv_e0) * LOG2E; cc1[i] = v; cc2[i] = v; }
}

// ---------- persistent fused softmin partial: work-stealing over (op,rb,chunk) units ----------
// NPERS blocks (3/CU) pull units off a global counter -> uniform 12 waves/CU for the
// whole phase (no grid-quantization remainder round). Per-unit body identical to the
// R15-verified hot loop (LDS-staged B, bf16 MFMA, diag patch, packed online-LSE).
__global__ __launch_bounds__(256)
void softmin_mfma4(P4 p4, const float* __restrict__ eps_list, int eps_idx,
                   int* __restrict__ counter, int rbmax, int nunits)
{
    __shared__ __bf16 yth[128 * YLD];
    __shared__ int u_sh;

    const int t    = threadIdx.x;
    const int lane = t & 63;
    const int w    = t >> 6;        // wave 0..3, owns 32 rows
    const int lx   = lane & 15;
    const int q    = lane >> 4;     // quad 0..3

    const float eps     = eps_list[eps_idx];
    const float inv_eps = 1.0f / eps;
    const float scale2  = inv_eps * LOG2E;
    const floatx2 s2v   = (floatx2){scale2, scale2};
    const floatx4 Z4    = (floatx4){0.f, 0.f, 0.f, 0.f};

    for (;;) {
        __syncthreads();            // previous unit's LDS readers done; u_sh reusable
        if (t == 0) u_sh = atomicAdd(counter, 1);
        __syncthreads();
        const int u = u_sh;
        if (u >= nunits) break;     // block-uniform exit

        const int op    = u / (rbmax * NCHUNK);
        const int rem   = u - op * (rbmax * NCHUNK);
        const int rb    = rem >> 3;            // NCHUNK == 8
        const int chunk = rem & (NCHUNK - 1);
        const OpDesc o  = p4.op[op];
        const int row0  = rb * BR;
        if (row0 >= o.n_rows) continue;
        const int cols_per_chunk = o.n_cols / NCHUNK;
        const int nsub = cols_per_chunk / 128;

        // A fragments: rows r0..r0+31, loaded once per unit (L2-hot)
        bf16x8 ah[2][2];
        {
            const int r0 = row0 + w * 32;
#pragma unroll
            for (int rt = 0; rt < 2; ++rt)
#pragma unroll
                for (int ks = 0; ks < 2; ++ks)
                    ah[rt][ks] = *(const bf16x8*)(o.xh + (size_t)(r0 + rt * 16 + lx) * D + ks * 32 + q * 8);
        }

        const int diag_blk = o.symmetric && ((row0 / cols_per_chunk) == chunk);
        float sqr[8];
        if (diag_blk) {
#pragma unroll
            for (int idx = 0; idx < 8; ++idx) {
                int row = row0 + w * 32 + (idx >> 2) * 16 + q * 4 + (idx & 3);
                sqr[idx] = o.sqn_col[row];
            }
        }

        float m[8], s[8];
#pragma unroll
        for (int i = 0; i < 8; ++i) { m[i] = -__builtin_inff(); s[i] = 0.0f; }

        for (int sub = 0; sub < nsub; ++sub) {
            const int col0 = chunk * cols_per_chunk + sub * 128;

            __syncthreads();   // previous tile's readers done
            {
                const uint4* gh = (const uint4*)(o.yh + (size_t)col0 * D);  // [128 rows][8 x 16B]
#pragma unroll
                for (int i = 0; i < 4; ++i) {
                    int c = t + i * 256;           // 0..1023
                    int row = c >> 3, part = c & 7;
                    uint4 vh = gh[c];
                    *(uint4*)(&yth[row * YLD + part * 8]) = vh;
                }
            }
            __syncthreads();   // tile ready

            float cc[8];
#pragma unroll
            for (int ct = 0; ct < 8; ++ct) cc[ct] = o.cc[col0 + ct * 16 + lx];

            floatx4 acc[8][2];
#pragma unroll
            for (int ct = 0; ct < 8; ++ct) {
                const int cl = ct * 16 + lx;
                bf16x8 bh0 = *(const bf16x8*)&yth[cl * YLD + q * 8];
                bf16x8 bh1 = *(const bf16x8*)&yth[cl * YLD + 32 + q * 8];
#pragma unroll
                for (int rt = 0; rt < 2; ++rt) {
                    floatx4 a = __builtin_amdgcn_mfma_f32_16x16x32_bf16(ah[rt][0], bh0, Z4, 0, 0, 0);
                    acc[ct][rt] = __builtin_amdgcn_mfma_f32_16x16x32_bf16(ah[rt][1], bh1, a, 0, 0, 0);
                }
            }

            // exact diagonal patch (self-term dominates LSE at small eps)
            if (diag_blk && col0 == row0) {
#pragma unroll
                for (int rt = 0; rt < 2; ++rt)
#pragma unroll
                    for (int r = 0; r < 4; ++r) {
                        if (lx == q * 4 + r) {
                            const float v = 2.0f * sqr[rt * 4 + r];
#pragma unroll
                            for (int ct = 0; ct < 8; ++ct)
                                if (ct == w * 2 + rt) acc[ct][rt][r] = v;
                        }
                    }
            }

            floatx2 ccv[4];
#pragma unroll
            for (int cp = 0; cp < 4; ++cp)
                ccv[cp] = (floatx2){cc[cp * 2], cc[cp * 2 + 1]};

            // epilogue: batched online-LSE, packed fp32 + native v_exp
            // C layout: acc[ct][rt][r] is row (rt*16 + q*4 + r), col (ct*16 + lx)
#pragma unroll
            for (int rt = 0; rt < 2; ++rt)
#pragma unroll
                for (int r = 0; r < 4; ++r) {
                    const int idx = rt * 4 + r;
                    floatx2 zv[4];
#pragma unroll
                    for (int cp = 0; cp < 4; ++cp) {
                        floatx2 av = (floatx2){acc[cp * 2][rt][r], acc[cp * 2 + 1][rt][r]};
                        zv[cp] = __builtin_elementwise_fma(av, s2v, ccv[cp]);
                    }
                    float M = max3f(zv[0].x, zv[0].y, zv[1].x);
                    M = max3f(M, zv[1].y, zv[2].x);
                    M = max3f(M, zv[2].y, zv[3].x);
                    M = max3f(M, zv[3].y, m[idx]);
                    const floatx2 Mv = (floatx2){M, M};
                    floatx2 sv = (floatx2){0.f, 0.f};
#pragma unroll
                    for (int cp = 0; cp < 4; ++cp) {
                        floatx2 dd = zv[cp] - Mv;
                        sv += (floatx2){exp2fast(dd.x), exp2fast(dd.y)};
                    }
                    s[idx] = fmaf(s[idx], exp2fast(m[idx] - M), sv.x + sv.y);
                    m[idx] = M;
                }
        }

        // reduce (m,s) across the 16 lanes sharing the same rows
#pragma unroll
        for (int idx = 0; idx < 8; ++idx) {
            float mm = m[idx], ss = s[idx];
#pragma unroll
            for (int d = 1; d < 16; d <<= 1) {
                float mo = __shfl_xor(mm, d, 64);
                float so = __shfl_xor(ss, d, 64);
                float M = fmaxf(mm, mo);
                ss = ss * exp2fast(mm - M) + so * exp2fast(mo - M);
                mm = M;
            }
            if (lx == 0) {
                const int rt = idx >> 2, r = idx & 3;
                const int row = row0 + w * 32 + rt * 16 + q * 4 + r;
                o.pm[chunk * o.n_rows + row] = mm;
                o.ps[chunk * o.n_rows + row] = ss;
            }
        }
    }
}

// ---------- fused merge: finish LSE, mix potential, emit next cc; reset counter ----------
__global__ void softmin_merge4(M4 m4, const float* __restrict__ eps_list,
                               int eps_idx, int eps_idx_next, int* __restrict__ counter)
{
    if (blockIdx.x == 0 && blockIdx.y == 0 && threadIdx.x == 0)
        counter[0] = 0;   // reset for the next phase's partial (stream-ordered)
    const MDesc o = m4.op[blockIdx.y];
    int i = blockIdx.x * blockDim.x + threadIdx.x;
    if (i >= o.n_rows) return;
    const float eps = eps_list[eps_idx];
    float M = -__builtin_inff();
    for (int c = 0; c < NCHUNK; ++c) M = fmaxf(M, o.pm[c * o.n_rows + i]);
    float S = 0.0f;
    for (int c = 0; c < NCHUNK; ++c) S += o.ps[c * o.n_rows + i] * exp2fast(o.pm[c * o.n_rows + i] - M);
    const float sq = o.sqn_row[i];
    float val = sq - eps * LN2 * (M + log2fast(S));
    float nv = o.mix ? 0.5f * (o.oldpot[i] + val) : val;
    o.newpot[i] = nv;
    if (o.ccout) {
        float inv_en = 1.0f / eps_list[eps_idx_next];
        o.ccout[i] = (o.wlog_c + (nv - sq) * inv_en) * LOG2E;
    }
}

__global__ void final_reduce(const float* __restrict__ f_ba_f, const float* __restrict__ f_aa_f,
                             const float* __restrict__ g_ab_f, const float* __restrict__ g_bb_f,
                             int n, int mcount, float* __restrict__ out)
{
    __shared__ float red[256];
    float s1 = 0.0f, s2 = 0.0f;
    for (int i = threadIdx.x; i < n; i += 256)      s1 += (f_ba_f[i] - f_aa_f[i]);
    for (int i = threadIdx.x; i < mcount; i += 256) s2 += (g_ab_f[i] - g_bb_f[i]);
    red[threadIdx.x] = s1 / (float)n + s2 / (float)mcount;
    __syncthreads();
    for (int off = 128; off > 0; off >>= 1) {
        if (threadIdx.x < off) red[threadIdx.x] += red[threadIdx.x + off];
        __syncthreads();
    }
    if (threadIdx.x == 0) out[0] = red[0];
}

extern "C" void kernel_launch(void* const* d_in, const int* in_sizes, int n_in,
                              void* d_out, int out_size, void* d_ws, size_t ws_size,
                              hipStream_t stream)
{
    const float* g        = (const float*)d_in[0];
    const float* Y        = (const float*)d_in[1];
    const float* eps_list = (const float*)d_in[2];
    const int N = in_sizes[0] / D;
    const int M = in_sizes[1] / D;
    const int L = in_sizes[2];
    const float a_log = -logf((float)N);
    const float b_log = -logf((float)M);
    const int NM = (N > M) ? N : M;
    const int rbmax = NM / BR;
    const int nunits = 4 * rbmax * NCHUNK;
    const size_t PMS = (size_t)NCHUNK * NM;

    unsigned short* us = (unsigned short*)d_ws;
    unsigned short* gxh = us; us += (size_t)N * D;
    unsigned short* gyh = us; us += (size_t)M * D;

    float* ws = (float*)us;
    float* sqn_x = ws; ws += N;
    float* sqn_y = ws; ws += M;
    float* fba[2]; fba[0] = ws; ws += N; fba[1] = ws; ws += N;
    float* gab[2]; gab[0] = ws; ws += M; gab[1] = ws; ws += M;
    float* fa[2];  fa[0]  = ws; ws += N; fa[1]  = ws; ws += N;
    float* gb[2];  gb[0]  = ws; ws += M; gb[1]  = ws; ws += M;
    float* f_ba_f = ws; ws += N;
    float* g_ab_f = ws; ws += M;
    float* f_aa_f = ws; ws += N;
    float* g_bb_f = ws; ws += M;
    float* cc[2][4];
    for (int pbuf = 0; pbuf < 2; ++pbuf)
        for (int i = 0; i < 4; ++i) { cc[pbuf][i] = ws; ws += NM; }
    float* pm = ws; ws += 4 * PMS;
    float* psb = ws; ws += 4 * PMS;
    int* counter = (int*)ws;

    sqnorm_kernel<<<(N + 255) / 256, 256, 0, stream>>>(g, sqn_x, N);
    sqnorm_kernel<<<(M + 255) / 256, 256, 0, stream>>>(Y, sqn_y, M);
    cvt_kernel<<<(N * D / 8 + 255) / 256, 256, 0, stream>>>(g, gxh, N * D / 8);
    cvt_kernel<<<(M * D / 8 + 255) / 256, 256, 0, stream>>>(Y, gyh, M * D / 8);
    init_cc_kernel<<<(NM + 255) / 256, 256, 0, stream>>>(sqn_x, sqn_y,
        cc[0][0], cc[0][1], cc[0][2], cc[0][3], eps_list, a_log, b_log, N, M, counter);

    // op order: 0 -> f_ba (rows x, cols y); 1 -> g_ab (rows y, cols x);
    //           2 -> f_aa (rows x, cols x); 3 -> g_bb (rows y, cols y)
    auto phase = [&](int eidx, int eidx_next, int mix, int cur, int ccp, int writecc,
                     float* out0, float* out1, float* out2, float* out3) {
        P4 p;
        p.op[0] = { gxh, gyh, cc[ccp][0], sqn_y, pm + 0 * PMS, psb + 0 * PMS, N, M, 0, 0 };
        p.op[1] = { gyh, gxh, cc[ccp][1], sqn_x, pm + 1 * PMS, psb + 1 * PMS, M, N, 0, 0 };
        p.op[2] = { gxh, gxh, cc[ccp][2], sqn_x, pm + 2 * PMS, psb + 2 * PMS, N, N, 1, 0 };
        p.op[3] = { gyh, gyh, cc[ccp][3], sqn_y, pm + 3 * PMS, psb + 3 * PMS, M, M, 1, 0 };
        softmin_mfma4<<<NPERS, 256, 0, stream>>>(p, eps_list, eidx, counter, rbmax, nunits);

        M4 mm;
        mm.op[0] = { pm + 0 * PMS, psb + 0 * PMS, sqn_x, fba[cur], out0,
                     writecc ? cc[ccp ^ 1][1] : nullptr, a_log, N, mix, 0 };
        mm.op[1] = { pm + 1 * PMS, psb + 1 * PMS, sqn_y, gab[cur], out1,
                     writecc ? cc[ccp ^ 1][0] : nullptr, b_log, M, mix, 0 };
        mm.op[2] = { pm + 2 * PMS, psb + 2 * PMS, sqn_x, fa[cur], out2,
                     writecc ? cc[ccp ^ 1][2] : nullptr, a_log, N, mix, 0 };
        mm.op[3] = { pm + 3 * PMS, psb + 3 * PMS, sqn_y, gb[cur], out3,
                     writecc ? cc[ccp ^ 1][3] : nullptr, b_log, M, mix, 0 };
        softmin_merge4<<<dim3((NM + 255) / 256, 4), 256, 0, stream>>>(mm, eps_list, eidx,
                                                                      eidx_next, counter);
    };

    phase(0, 0, 0, 0, 0, 1, fba[0], gab[0], fa[0], gb[0]);
    int cur = 0, ccp = 1;

    for (int k = 0; k < L; ++k) {
        int en = (k + 1 < L) ? (k + 1) : (L - 1);
        phase(k, en, 1, cur, ccp, 1, fba[cur ^ 1], gab[cur ^ 1], fa[cur ^ 1], gb[cur ^ 1]);
        cur ^= 1; ccp ^= 1;
    }

    phase(L - 1, L - 1, 0, cur, ccp, 0, f_ba_f, g_ab_f, f_aa_f, g_bb_f);

    final_reduce<<<1, 256, 0, stream>>>(f_ba_f, f_aa_f, g_ab_f, g_bb_f, N, M, (float*)d_out);
}

// Round 17
// 1211.395 us; speedup vs baseline: 1.2076x; 1.2076x over previous
//
#include <hip/hip_runtime.h>
#include <math.h>

#define D 64
#define BR 128          // rows per block
#define NCHUNK 4        // column chunks (grid.y) — 2048 cols/chunk, 16 sub-tiles/block
#define YLD 72          // y-tile row stride in bf16 (64 + 8 pad -> 2-way banks only)
#define LOG2E 1.4426950408889634f
#define LN2   0.6931471805599453f

typedef __attribute__((ext_vector_type(8))) __bf16 bf16x8;
typedef __attribute__((ext_vector_type(4))) float  floatx4;
typedef __attribute__((ext_vector_type(2))) float  floatx2;

static __device__ __forceinline__ float exp2fast(float x) {
#if __has_builtin(__builtin_amdgcn_exp2f)
    return __builtin_amdgcn_exp2f(x);
#else
    return exp2f(x);
#endif
}
static __device__ __forceinline__ float log2fast(float x) {
#if __has_builtin(__builtin_amdgcn_logf)
    return __builtin_amdgcn_logf(x);
#else
    return log2f(x);
#endif
}
static __device__ __forceinline__ float max3f(float a, float b, float c) {
    return fmaxf(fmaxf(a, b), c);   // folds to v_max3_f32
}

static __device__ __forceinline__ unsigned short f2bf_rne(float f) {
    unsigned u = __float_as_uint(f);
    return (unsigned short)((u + 0x7fffu + ((u >> 16) & 1u)) >> 16);
}

// ---------- op descriptors ----------
struct OpDesc {
    const unsigned short* xh;   // [n_rows][64] bf16 row points
    const unsigned short* yh;   // [n_cols][64] bf16 col points
    const float* cc;            // [n_cols] log2-domain col constants
    const float* sqn_col;       // [n_cols]
    float* pm; float* ps;       // [NCHUNK][n_rows]
    int n_rows, n_cols, symmetric, pad;
};
struct P4 { OpDesc op[4]; };

struct MDesc {
    const float* pm; const float* ps;
    const float* sqn_row;
    const float* oldpot;
    float* newpot;
    float* ccout;               // next phase's col constants (crosswired) or null
    float wlog_c;
    int n_rows, mix, pad;
};
struct M4 { MDesc op[4]; };

// ---------- prep kernels ----------
__global__ void cvt_kernel(const float* __restrict__ x,
                           unsigned short* __restrict__ xh, int n_elem8)
{
    int i = blockIdx.x * blockDim.x + threadIdx.x;
    if (i >= n_elem8) return;
    const float4* xp = (const float4*)x;
    float4 v0 = xp[i * 2], v1 = xp[i * 2 + 1];
    float v[8] = {v0.x, v0.y, v0.z, v0.w, v1.x, v1.y, v1.z, v1.w};
    unsigned h[8];
#pragma unroll
    for (int k = 0; k < 8; ++k) h[k] = f2bf_rne(v[k]);
    uint4 ph;
    ph.x = h[0] | (h[1] << 16); ph.y = h[2] | (h[3] << 16);
    ph.z = h[4] | (h[5] << 16); ph.w = h[6] | (h[7] << 16);
    ((uint4*)xh)[i] = ph;
}

__global__ void sqnorm_kernel(const float* __restrict__ x, float* __restrict__ sqn, int n)
{
    int i = blockIdx.x * blockDim.x + threadIdx.x;
    if (i >= n) return;
    const float4* xp = (const float4*)(x + (size_t)i * D);
    float sum = 0.0f;
#pragma unroll
    for (int k = 0; k < D / 4; ++k) {
        float4 v = xp[k];
        sum += v.x * v.x + v.y * v.y + v.z * v.z + v.w * v.w;
    }
    sqn[i] = 0.5f * sum;
}

__global__ void init_cc_kernel(const float* __restrict__ sqn_x, const float* __restrict__ sqn_y,
                               float* cc0, float* cc1, float* cc2, float* cc3,
                               const float* __restrict__ eps_list,
                               float a_log, float b_log, int N, int M)
{
    int i = blockIdx.x * blockDim.x + threadIdx.x;
    float inv_e0 = 1.0f / eps_list[0];
    if (i < M) { float v = (b_log - sqn_y[i] * inv_e0) * LOG2E; cc0[i] = v; cc3[i] = v; }
    if (i < N) { float v = (a_log - sqn_x[i] * inv_e0) * LOG2E; cc1[i] = v; cc2[i] = v; }
}

// ---------- fused softmin partial: LDS-staged B, 4 ops via blockIdx.z (R13/R15-proven) ----------
__global__ __launch_bounds__(256)
void softmin_mfma4(P4 p4, const float* __restrict__ eps_list, int eps_idx)
{
    __shared__ __bf16 yth[128 * YLD];

    const OpDesc o = p4.op[blockIdx.z];
    const int t    = threadIdx.x;
    const int lane = t & 63;
    const int w    = t >> 6;        // wave 0..3, owns 32 rows
    const int lx   = lane & 15;
    const int q    = lane >> 4;     // quad 0..3
    const int row0 = blockIdx.x * BR;
    const int chunk = blockIdx.y;
    const int cols_per_chunk = o.n_cols / NCHUNK;
    const int nsub = cols_per_chunk / 128;

    const float eps     = eps_list[eps_idx];
    const float inv_eps = 1.0f / eps;
    const float scale2  = inv_eps * LOG2E;
    const floatx2 s2v   = (floatx2){scale2, scale2};
    const floatx4 Z4    = (floatx4){0.f, 0.f, 0.f, 0.f};

    // A fragments: rows r0..r0+31, loaded once, reused for every column
    bf16x8 ah[2][2];
    {
        const int r0 = row0 + w * 32;
#pragma unroll
        for (int rt = 0; rt < 2; ++rt)
#pragma unroll
            for (int ks = 0; ks < 2; ++ks)
                ah[rt][ks] = *(const bf16x8*)(o.xh + (size_t)(r0 + rt * 16 + lx) * D + ks * 32 + q * 8);
    }

    const int diag_blk = o.symmetric && ((row0 / cols_per_chunk) == chunk);
    float sqr[8];
    if (diag_blk) {
#pragma unroll
        for (int idx = 0; idx < 8; ++idx) {
            int row = row0 + w * 32 + (idx >> 2) * 16 + q * 4 + (idx & 3);
            sqr[idx] = o.sqn_col[row];
        }
    }

    float m[8], s[8];
#pragma unroll
    for (int i = 0; i < 8; ++i) { m[i] = -__builtin_inff(); s[i] = 0.0f; }

    for (int sub = 0; sub < nsub; ++sub) {
        const int col0 = chunk * cols_per_chunk + sub * 128;

        __syncthreads();   // previous tile's readers done
        {
            const uint4* gh = (const uint4*)(o.yh + (size_t)col0 * D);  // [128 rows][8 x 16B]
#pragma unroll
            for (int i = 0; i < 4; ++i) {
                int c = t + i * 256;           // 0..1023
                int row = c >> 3, part = c & 7;
                uint4 vh = gh[c];
                *(uint4*)(&yth[row * YLD + part * 8]) = vh;
            }
        }
        __syncthreads();   // tile ready

        float cc[8];
#pragma unroll
        for (int ct = 0; ct < 8; ++ct) cc[ct] = o.cc[col0 + ct * 16 + lx];

        floatx4 acc[8][2];
#pragma unroll
        for (int ct = 0; ct < 8; ++ct) {
            const int cl = ct * 16 + lx;
            bf16x8 bh0 = *(const bf16x8*)&yth[cl * YLD + q * 8];
            bf16x8 bh1 = *(const bf16x8*)&yth[cl * YLD + 32 + q * 8];
#pragma unroll
            for (int rt = 0; rt < 2; ++rt) {
                floatx4 a = __builtin_amdgcn_mfma_f32_16x16x32_bf16(ah[rt][0], bh0, Z4, 0, 0, 0);
                acc[ct][rt] = __builtin_amdgcn_mfma_f32_16x16x32_bf16(ah[rt][1], bh1, a, 0, 0, 0);
            }
        }

        // exact diagonal patch (self-term dominates LSE at small eps)
        if (diag_blk && col0 == row0) {
#pragma unroll
            for (int rt = 0; rt < 2; ++rt)
#pragma unroll
                for (int r = 0; r < 4; ++r) {
                    if (lx == q * 4 + r) {
                        const float v = 2.0f * sqr[rt * 4 + r];
#pragma unroll
                        for (int ct = 0; ct < 8; ++ct)
                            if (ct == w * 2 + rt) acc[ct][rt][r] = v;
                    }
                }
        }

        floatx2 ccv[4];
#pragma unroll
        for (int cp = 0; cp < 4; ++cp)
            ccv[cp] = (floatx2){cc[cp * 2], cc[cp * 2 + 1]};

        // epilogue: batched online-LSE, packed fp32 + native v_exp
        // C layout: acc[ct][rt][r] is row (rt*16 + q*4 + r), col (ct*16 + lx)
#pragma unroll
        for (int rt = 0; rt < 2; ++rt)
#pragma unroll
            for (int r = 0; r < 4; ++r) {
                const int idx = rt * 4 + r;
                floatx2 zv[4];
#pragma unroll
                for (int cp = 0; cp < 4; ++cp) {
                    floatx2 av = (floatx2){acc[cp * 2][rt][r], acc[cp * 2 + 1][rt][r]};
                    zv[cp] = __builtin_elementwise_fma(av, s2v, ccv[cp]);
                }
                float M = max3f(zv[0].x, zv[0].y, zv[1].x);
                M = max3f(M, zv[1].y, zv[2].x);
                M = max3f(M, zv[2].y, zv[3].x);
                M = max3f(M, zv[3].y, m[idx]);
                const floatx2 Mv = (floatx2){M, M};
                floatx2 sv = (floatx2){0.f, 0.f};
#pragma unroll
                for (int cp = 0; cp < 4; ++cp) {
                    floatx2 dd = zv[cp] - Mv;
                    sv += (floatx2){exp2fast(dd.x), exp2fast(dd.y)};
                }
                s[idx] = fmaf(s[idx], exp2fast(m[idx] - M), sv.x + sv.y);
                m[idx] = M;
            }
    }

    // reduce (m,s) across the 16 lanes sharing the same rows
#pragma unroll
    for (int idx = 0; idx < 8; ++idx) {
        float mm = m[idx], ss = s[idx];
#pragma unroll
        for (int d = 1; d < 16; d <<= 1) {
            float mo = __shfl_xor(mm, d, 64);
            float so = __shfl_xor(ss, d, 64);
            float M = fmaxf(mm, mo);
            ss = ss * exp2fast(mm - M) + so * exp2fast(mo - M);
            mm = M;
        }
        if (lx == 0) {
            const int rt = idx >> 2, r = idx & 3;
            const int row = row0 + w * 32 + rt * 16 + q * 4 + r;
            o.pm[chunk * o.n_rows + row] = mm;
            o.ps[chunk * o.n_rows + row] = ss;
        }
    }
}

// ---------- fused merge: finish LSE, mix potential, emit next phase's cc ----------
__global__ void softmin_merge4(M4 m4, const float* __restrict__ eps_list,
                               int eps_idx, int eps_idx_next)
{
    const MDesc o = m4.op[blockIdx.y];
    int i = blockIdx.x * blockDim.x + threadIdx.x;
    if (i >= o.n_rows) return;
    const float eps = eps_list[eps_idx];
    float M = -__builtin_inff();
    for (int c = 0; c < NCHUNK; ++c) M = fmaxf(M, o.pm[c * o.n_rows + i]);
    float S = 0.0f;
    for (int c = 0; c < NCHUNK; ++c) S += o.ps[c * o.n_rows + i] * exp2fast(o.pm[c * o.n_rows + i] - M);
    const float sq = o.sqn_row[i];
    float val = sq - eps * LN2 * (M + log2fast(S));
    float nv = o.mix ? 0.5f * (o.oldpot[i] + val) : val;
    o.newpot[i] = nv;
    if (o.ccout) {
        float inv_en = 1.0f / eps_list[eps_idx_next];
        o.ccout[i] = (o.wlog_c + (nv - sq) * inv_en) * LOG2E;
    }
}

__global__ void final_reduce(const float* __restrict__ f_ba_f, const float* __restrict__ f_aa_f,
                             const float* __restrict__ g_ab_f, const float* __restrict__ g_bb_f,
                             int n, int mcount, float* __restrict__ out)
{
    __shared__ float red[256];
    float s1 = 0.0f, s2 = 0.0f;
    for (int i = threadIdx.x; i < n; i += 256)      s1 += (f_ba_f[i] - f_aa_f[i]);
    for (int i = threadIdx.x; i < mcount; i += 256) s2 += (g_ab_f[i] - g_bb_f[i]);
    red[threadIdx.x] = s1 / (float)n + s2 / (float)mcount;
    __syncthreads();
    for (int off = 128; off > 0; off >>= 1) {
        if (threadIdx.x < off) red[threadIdx.x] += red[threadIdx.x + off];
        __syncthreads();
    }
    if (threadIdx.x == 0) out[0] = red[0];
}

extern "C" void kernel_launch(void* const* d_in, const int* in_sizes, int n_in,
                              void* d_out, int out_size, void* d_ws, size_t ws_size,
                              hipStream_t stream)
{
    const float* g        = (const float*)d_in[0];
    const float* Y        = (const float*)d_in[1];
    const float* eps_list = (const float*)d_in[2];
    const int N = in_sizes[0] / D;
    const int M = in_sizes[1] / D;
    const int L = in_sizes[2];
    const float a_log = -logf((float)N);
    const float b_log = -logf((float)M);
    const int NM = (N > M) ? N : M;
    const size_t PMS = (size_t)NCHUNK * NM;

    unsigned short* us = (unsigned short*)d_ws;
    unsigned short* gxh = us; us += (size_t)N * D;
    unsigned short* gyh = us; us += (size_t)M * D;

    float* ws = (float*)us;
    float* sqn_x = ws; ws += N;
    float* sqn_y = ws; ws += M;
    float* fba[2]; fba[0] = ws; ws += N; fba[1] = ws; ws += N;
    float* gab[2]; gab[0] = ws; ws += M; gab[1] = ws; ws += M;
    float* fa[2];  fa[0]  = ws; ws += N; fa[1]  = ws; ws += N;
    float* gb[2];  gb[0]  = ws; ws += M; gb[1]  = ws; ws += M;
    float* f_ba_f = ws; ws += N;
    float* g_ab_f = ws; ws += M;
    float* f_aa_f = ws; ws += N;
    float* g_bb_f = ws; ws += M;
    float* cc[2][4];
    for (int pbuf = 0; pbuf < 2; ++pbuf)
        for (int i = 0; i < 4; ++i) { cc[pbuf][i] = ws; ws += NM; }
    float* pm = ws; ws += 4 * PMS;
    float* psb = ws; ws += 4 * PMS;

    sqnorm_kernel<<<(N + 255) / 256, 256, 0, stream>>>(g, sqn_x, N);
    sqnorm_kernel<<<(M + 255) / 256, 256, 0, stream>>>(Y, sqn_y, M);
    cvt_kernel<<<(N * D / 8 + 255) / 256, 256, 0, stream>>>(g, gxh, N * D / 8);
    cvt_kernel<<<(M * D / 8 + 255) / 256, 256, 0, stream>>>(Y, gyh, M * D / 8);
    init_cc_kernel<<<(NM + 255) / 256, 256, 0, stream>>>(sqn_x, sqn_y,
        cc[0][0], cc[0][1], cc[0][2], cc[0][3], eps_list, a_log, b_log, N, M);

    // op order: 0 -> f_ba (rows x, cols y); 1 -> g_ab (rows y, cols x);
    //           2 -> f_aa (rows x, cols x); 3 -> g_bb (rows y, cols y)
    auto phase = [&](int eidx, int eidx_next, int mix, int cur, int ccp, int writecc,
                     float* out0, float* out1, float* out2, float* out3) {
        P4 p;
        p.op[0] = { gxh, gyh, cc[ccp][0], sqn_y, pm + 0 * PMS, psb + 0 * PMS, N, M, 0, 0 };
        p.op[1] = { gyh, gxh, cc[ccp][1], sqn_x, pm + 1 * PMS, psb + 1 * PMS, M, N, 0, 0 };
        p.op[2] = { gxh, gxh, cc[ccp][2], sqn_x, pm + 2 * PMS, psb + 2 * PMS, N, N, 1, 0 };
        p.op[3] = { gyh, gyh, cc[ccp][3], sqn_y, pm + 3 * PMS, psb + 3 * PMS, M, M, 1, 0 };
        softmin_mfma4<<<dim3(NM / BR, NCHUNK, 4), 256, 0, stream>>>(p, eps_list, eidx);

        M4 mm;
        mm.op[0] = { pm + 0 * PMS, psb + 0 * PMS, sqn_x, fba[cur], out0,
                     writecc ? cc[ccp ^ 1][1] : nullptr, a_log, N, mix, 0 };
        mm.op[1] = { pm + 1 * PMS, psb + 1 * PMS, sqn_y, gab[cur], out1,
                     writecc ? cc[ccp ^ 1][0] : nullptr, b_log, M, mix, 0 };
        mm.op[2] = { pm + 2 * PMS, psb + 2 * PMS, sqn_x, fa[cur], out2,
                     writecc ? cc[ccp ^ 1][2] : nullptr, a_log, N, mix, 0 };
        mm.op[3] = { pm + 3 * PMS, psb + 3 * PMS, sqn_y, gb[cur], out3,
                     writecc ? cc[ccp ^ 1][3] : nullptr, b_log, M, mix, 0 };
        softmin_merge4<<<dim3((NM + 255) / 256, 4), 256, 0, stream>>>(mm, eps_list, eidx, eidx_next);
    };

    phase(0, 0, 0, 0, 0, 1, fba[0], gab[0], fa[0], gb[0]);
    int cur = 0, ccp = 1;

    for (int k = 0; k < L; ++k) {
        int en = (k + 1 < L) ? (k + 1) : (L - 1);
        phase(k, en, 1, cur, ccp, 1, fba[cur ^ 1], gab[cur ^ 1], fa[cur ^ 1], gb[cur ^ 1]);
        cur ^= 1; ccp ^= 1;
    }

    phase(L - 1, L - 1, 0, cur, ccp, 0, f_ba_f, g_ab_f, f_aa_f, g_bb_f);

    final_reduce<<<1, 256, 0, stream>>>(f_ba_f, f_aa_f, g_ab_f, g_bb_f, N, M, (float*)d_out);
}